// Round 6
// baseline (1142.080 us; speedup 1.0000x reference)
//
#include <hip/hip_runtime.h>
#include <math.h>

#define TPB 512        // 8 waves: wave w owns row-tile (w + t*8)
#define E 16           // elements per block
#define VSTR 264       // [e][k] stride for vector-activation LDS buffers (f16)
#define PLANE (E * VSTR)
#define SSTR 392       // scat stride
#define OSTR 136       // souts stride
#define SLOPE_VN 0.2f
#define SLOPE_SCA 0.01f
#define EPS_VN 1e-6f

using hfrag = __attribute__((ext_vector_type(8))) _Float16;
using h4    = __attribute__((ext_vector_type(4))) _Float16;
using ffrag = __attribute__((ext_vector_type(4))) float;

__device__ __forceinline__ ffrag mfma(hfrag a, hfrag b, ffrag c) {
  return __builtin_amdgcn_mfma_f32_16x16x32_f16(a, b, c, 0, 0, 0);
}

// LLVM SchedGroupMask: MFMA=0x8, VMEM_READ=0x20, DS_READ=0x100
#define SGB __builtin_amdgcn_sched_group_barrier

// ---- f16 weight pointers (into d_ws) ----
struct WB {
  const _Float16 *g1_Wvh,*g1_Ws,*g1_Wvo,*g1_Wg,*g1_Wd;
  const _Float16 *g2_Wvh,*g2_Ws,*g2_Wvo,*g2_Wg;
  const _Float16 *a1_Wvh,*a1_Ws,*a1_Wvo,*a1_Wg,*a1_Wd;
  const _Float16 *a2_Wvh,*a2_Ws,*a2_Wvo,*a2_Wg,*a2_Wd;
  const _Float16 *f_Wvh;
  const float *g1_bg,*g2_bg,*a1_bg,*a2_bg,*f_Ws;
};

// ---- weight f32->f16 conversion pre-pass ----
struct CvtJobs { const float* src[20]; _Float16* dst[20]; int n[20]; };

__global__ void cvt_kernel(CvtJobs J) {
  const int j = blockIdx.y;
  const float* __restrict__ s = J.src[j];
  _Float16* __restrict__ d = J.dst[j];
  const int n = J.n[j];
  for (int i = blockIdx.x * blockDim.x + threadIdx.x; i < n;
       i += gridDim.x * blockDim.x)
    d[i] = (_Float16)s[i];
}

// ---- GEMM helpers ----
// All KS*TT weight fragments are preloaded; sched_group_barrier pins the
// final schedule to: [all global loads] then per k-slice [ds_reads + mfmas].
// This exposes ONE L2 latency per gemm instead of KS*TT serialized ones.

// Vector GEMM: acc[t][c] += W[O][C] * v_c, tiles = wave + 8*t.
template<int TT, int KS>
__device__ __forceinline__ void gemmV(const _Float16* __restrict__ W, int C,
                                      const _Float16* vb, ffrag acc[TT][3]) {
  const int m = threadIdx.x & 15;
  const int q = (threadIdx.x >> 4) & 3;
  const int w = threadIdx.x >> 6;
  hfrag a[KS][TT];
  #pragma unroll
  for (int ks = 0; ks < KS; ++ks)
    #pragma unroll
    for (int t = 0; t < TT; ++t)
      a[ks][t] = *(const hfrag*)(W + (size_t)((w + t * 8) * 16 + m) * C + ks * 32 + q * 8);
  #pragma unroll
  for (int ks = 0; ks < KS; ++ks) {
    const int k = ks * 32 + q * 8;
    hfrag b0 = *(const hfrag*)(vb + 0 * PLANE + m * VSTR + k);
    hfrag b1 = *(const hfrag*)(vb + 1 * PLANE + m * VSTR + k);
    hfrag b2 = *(const hfrag*)(vb + 2 * PLANE + m * VSTR + k);
    #pragma unroll
    for (int t = 0; t < TT; ++t) {
      acc[t][0] = mfma(a[ks][t], b0, acc[t][0]);
      acc[t][1] = mfma(a[ks][t], b1, acc[t][1]);
      acc[t][2] = mfma(a[ks][t], b2, acc[t][2]);
    }
  }
  SGB(0x020, KS * TT, 0);           // all weight loads back-to-back
  #pragma unroll
  for (int ks = 0; ks < KS; ++ks) {
    SGB(0x100, 3, 0);               // 3 LDS b-reads
    SGB(0x008, TT * 3, 0);          // then their mfmas
  }
}

// Scalar GEMM: acc[t] += W[O][C] * s
template<int TT, int KS>
__device__ __forceinline__ void gemmS(const _Float16* __restrict__ W, int C,
                                      const _Float16* sb, int sstr, ffrag acc[TT]) {
  const int m = threadIdx.x & 15;
  const int q = (threadIdx.x >> 4) & 3;
  const int w = threadIdx.x >> 6;
  hfrag a[KS][TT];
  #pragma unroll
  for (int ks = 0; ks < KS; ++ks)
    #pragma unroll
    for (int t = 0; t < TT; ++t)
      a[ks][t] = *(const hfrag*)(W + (size_t)((w + t * 8) * 16 + m) * C + ks * 32 + q * 8);
  #pragma unroll
  for (int ks = 0; ks < KS; ++ks) {
    const int k = ks * 32 + q * 8;
    hfrag b = *(const hfrag*)(sb + m * sstr + k);
    #pragma unroll
    for (int t = 0; t < TT; ++t)
      acc[t] = mfma(a[ks][t], b, acc[t]);
  }
  SGB(0x020, KS * TT, 0);
  #pragma unroll
  for (int ks = 0; ks < KS; ++ks) {
    SGB(0x100, 1, 0);
    SGB(0x008, TT, 0);
  }
}

// Store a C/D fragment into an [e][k] LDS buffer (4 consecutive k = rows).
__device__ __forceinline__ void stCD(_Float16* buf, int stride, int tile, ffrag v) {
  const int e = threadIdx.x & 15;
  const int q = (threadIdx.x >> 4) & 3;
  h4 p;
  p[0] = (_Float16)v[0]; p[1] = (_Float16)v[1];
  p[2] = (_Float16)v[2]; p[3] = (_Float16)v[3];
  *(h4*)(buf + e * stride + tile * 16 + q * 4) = p;
}

// Re-load a C/D fragment (this wave's own tile) from LDS.
__device__ __forceinline__ ffrag ldCD(const _Float16* buf, int stride, int tile) {
  const int e = threadIdx.x & 15;
  const int q = (threadIdx.x >> 4) & 3;
  h4 p = *(const h4*)(buf + e * stride + tile * 16 + q * 4);
  ffrag v;
  v[0] = (float)p[0]; v[1] = (float)p[1]; v[2] = (float)p[2]; v[3] = (float)p[3];
  return v;
}

__device__ __forceinline__ float sigm(float x) { return 1.f / (1.f + expf(-x)); }

// vn_leaky on re-read x (f16, self-consistent with Wd input) + d, store result.
__device__ __forceinline__ void vnLeakyStore(_Float16* sv, int tile,
                                             ffrag d0, ffrag d1, ffrag d2) {
  ffrag x0 = ldCD(sv + 0 * PLANE, VSTR, tile);
  ffrag x1 = ldCD(sv + 1 * PLANE, VSTR, tile);
  ffrag x2 = ldCD(sv + 2 * PLANE, VSTR, tile);
  #pragma unroll
  for (int r = 0; r < 4; ++r) {
    float dot = x0[r]*d0[r] + x1[r]*d1[r] + x2[r]*d2[r];
    float kk = dot / (d0[r]*d0[r] + d1[r]*d1[r] + d2[r]*d2[r] + EPS_VN);
    if (dot < 0.f) {
      x0[r] = SLOPE_VN*x0[r] + (1.f-SLOPE_VN)*(x0[r] - kk*d0[r]);
      x1[r] = SLOPE_VN*x1[r] + (1.f-SLOPE_VN)*(x1[r] - kk*d1[r]);
      x2[r] = SLOPE_VN*x2[r] + (1.f-SLOPE_VN)*(x2[r] - kk*d2[r]);
    }
  }
  stCD(sv + 0 * PLANE, VSTR, tile, x0);
  stCD(sv + 1 * PLANE, VSTR, tile, x1);
  stCD(sv + 2 * PLANE, VSTR, tile, x2);
}

__global__ __launch_bounds__(TPB, 4) void pe_kernel(
    const float* __restrict__ h_sca, const float* __restrict__ h_vec,
    const float* __restrict__ pos_compose, const float* __restrict__ pos,
    WB W, const int* __restrict__ idx_focal, float* __restrict__ out, int F) {
  // sv: [comp][e][k<264]. Region use per layer:
  //   g1: v_in [0:64], vh [64:192], v_new/final [0:128]
  //   g2: v_in [0:128], vh [128:256], v_final [0:128]
  //   a1: v_in [0:128], vh/v_new/v1 [0:256]
  //   a2: v_in [0:128], vh [128:256], v_new/final [0:128]
  // scat: [e][k<392]:
  //   g1 Ws in: vnorm[0:128]|s_in[128:384];  g1 act_s -> [128:256]
  //   g2 Ws in: vnorm[0:128]|act_s[128:256]; g2 raw_so -> [256:384]
  //   a1 Ws in: vnorm[0:256]|raw_so_g2[256:384]; a1 act_s1 -> [128:256]
  //   a2 Ws in: vnorm[0:128]|s1[128:256]|inner[256:384]; a2 act_s -> [128:256]
  //   f  in:    vnorm[0:128]|act_s[128:256]
  __shared__ _Float16 sv [3 * PLANE];
  __shared__ _Float16 scat[E * SSTR];
  __shared__ _Float16 souts[E * OSTR];    // raw out_s (g1/a1/a2)
  __shared__ float srel[E * 3];

  const int t = threadIdx.x;
  const int wv = t >> 6;          // 0..7
  const int q = (t >> 4) & 3;
  const int el = t >> 5;          // gather: element handled by 32 threads
  const int c5 = t & 31;
  const int eg = blockIdx.x * E + el;

  // ======== gather (f32 -> f16 LDS, float4 loads, h4 stores) ========
  {
    const int idx = (eg < F) ? idx_focal[eg] : 0;
    if (c5 < 16) {
      const float4* __restrict__ vsrc = (const float4*)(h_vec + (size_t)idx * 192);
      const float4 va = vsrc[3 * c5 + 0];
      const float4 vb = vsrc[3 * c5 + 1];
      const float4 vc = vsrc[3 * c5 + 2];
      const float f[12] = {va.x, va.y, va.z, va.w, vb.x, vb.y, vb.z, vb.w,
                           vc.x, vc.y, vc.z, vc.w};
      #pragma unroll
      for (int comp = 0; comp < 3; ++comp) {
        h4 p;
        p[0] = (_Float16)f[0 + comp]; p[1] = (_Float16)f[3 + comp];
        p[2] = (_Float16)f[6 + comp]; p[3] = (_Float16)f[9 + comp];
        *(h4*)(sv + comp * PLANE + el * VSTR + 4 * c5) = p;
      }
      if (c5 < 3 && eg < F)
        srel[el * 3 + c5] = pos[(size_t)eg * 3 + c5] - pos_compose[(size_t)idx * 3 + c5];
    } else {
      const int u = c5 - 16;
      const float4* __restrict__ ssrc = (const float4*)(h_sca + (size_t)idx * 256);
      #pragma unroll
      for (int i2 = 0; i2 < 4; ++i2) {
        const float4 vv = ssrc[4 * u + i2];
        h4 p;
        p[0] = (_Float16)vv.x; p[1] = (_Float16)vv.y;
        p[2] = (_Float16)vv.z; p[3] = (_Float16)vv.w;
        *(h4*)(scat + el * SSTR + 128 + 16 * u + 4 * i2) = p;
      }
    }
  }
  __syncthreads();

  ffrag zero = {0.f, 0.f, 0.f, 0.f};

  // ================= g1: perceptron (C=64 -> H=128 -> O=128) =================
  {
    // A: vh = Wvh @ v_in; vh -> sv[64:192] (not read here), vnorm -> scat[0:128]
    ffrag vh[1][3];
    for (int c = 0; c < 3; ++c) vh[0][c] = zero;
    gemmV<1, 2>(W.g1_Wvh, 64, sv, vh);
    for (int c = 0; c < 3; ++c) stCD(sv + c * PLANE + 64, VSTR, wv, vh[0][c]);
    {
      ffrag n;
      #pragma unroll
      for (int r = 0; r < 4; ++r)
        n[r] = sqrtf(vh[0][0][r]*vh[0][0][r] + vh[0][1][r]*vh[0][1][r] + vh[0][2][r]*vh[0][2][r]);
      stCD(scat, SSTR, wv, n);
    }
    __syncthreads();

    // B: so = Ws @ scat[0:384]; ov = Wvo @ vh; raw_so -> souts
    ffrag so[1]; so[0] = zero;
    ffrag ov[1][3];
    for (int c = 0; c < 3; ++c) ov[0][c] = zero;
    gemmS<1, 12>(W.g1_Ws, 384, scat, SSTR, so);
    gemmV<1, 4>(W.g1_Wvo, 128, sv + 64, ov);
    stCD(souts, OSTR, wv, so[0]);
    __syncthreads();

    // C: g = Wg @ souts; gate; v_new -> sv[0:128]; act_s -> scat[128:256]
    ffrag g[1]; g[0] = zero;
    gemmS<1, 4>(W.g1_Wg, 128, souts, OSTR, g);
    {
      const float4 b = *(const float4*)(W.g1_bg + wv * 16 + q * 4);
      const float bb[4] = {b.x, b.y, b.z, b.w};
      #pragma unroll
      for (int r = 0; r < 4; ++r) {
        float gg = sigm(g[0][r] + bb[r]);
        ov[0][0][r] *= gg; ov[0][1][r] *= gg; ov[0][2][r] *= gg;
      }
      for (int c = 0; c < 3; ++c) stCD(sv + c * PLANE, VSTR, wv, ov[0][c]);
      ffrag l;
      for (int r = 0; r < 4; ++r) { float x = so[0][r]; l[r] = x >= 0.f ? x : SLOPE_SCA * x; }
      stCD(scat + 128, SSTR, wv, l);
    }
    __syncthreads();

    // D: d = Wd @ v_new
    ffrag d[1][3];
    for (int c = 0; c < 3; ++c) d[0][c] = zero;
    gemmV<1, 4>(W.g1_Wd, 128, sv, d);
    __syncthreads();

    // E: vn_leaky (x re-read from sv), v_final -> sv[0:128]
    vnLeakyStore(sv, wv, d[0][0], d[0][1], d[0][2]);
    __syncthreads();
  }

  // ================= g2: linear (128 -> 128) =================
  {
    // A: vh -> sv[128:256]; vnorm -> scat[0:128]
    ffrag vh[1][3];
    for (int c = 0; c < 3; ++c) vh[0][c] = zero;
    gemmV<1, 4>(W.g2_Wvh, 128, sv, vh);
    for (int c = 0; c < 3; ++c) stCD(sv + c * PLANE + 128, VSTR, wv, vh[0][c]);
    {
      ffrag n;
      for (int r = 0; r < 4; ++r)
        n[r] = sqrtf(vh[0][0][r]*vh[0][0][r] + vh[0][1][r]*vh[0][1][r] + vh[0][2][r]*vh[0][2][r]);
      stCD(scat, SSTR, wv, n);
    }
    __syncthreads();

    // B: so = Ws @ scat[0:256]; ov = Wvo @ vh; raw_so -> scat[256:384] (a1 input + Wg input)
    ffrag so[1]; so[0] = zero;
    ffrag ov[1][3];
    for (int c = 0; c < 3; ++c) ov[0][c] = zero;
    gemmS<1, 8>(W.g2_Ws, 256, scat, SSTR, so);
    gemmV<1, 4>(W.g2_Wvo, 128, sv + 128, ov);
    stCD(scat + 256, SSTR, wv, so[0]);
    __syncthreads();

    // C: g = Wg @ scat[256:384]; gate; v_final -> sv[0:128]
    ffrag g[1]; g[0] = zero;
    gemmS<1, 4>(W.g2_Wg, 128, scat + 256, SSTR, g);
    {
      const float4 b = *(const float4*)(W.g2_bg + wv * 16 + q * 4);
      const float bb[4] = {b.x, b.y, b.z, b.w};
      for (int r = 0; r < 4; ++r) {
        float gg = sigm(g[0][r] + bb[r]);
        ov[0][0][r] *= gg; ov[0][1][r] *= gg; ov[0][2][r] *= gg;
      }
      for (int c = 0; c < 3; ++c) stCD(sv + c * PLANE, VSTR, wv, ov[0][c]);
    }
    __syncthreads();
  }

  // ================= a1: perceptron (128 -> H=256 -> O=256) =================
  {
    // A: vh[2] = Wvh @ v (needs [0:256], overlaps v_in -> barrier then store)
    ffrag vh[2][3];
    #pragma unroll
    for (int i = 0; i < 2; ++i) for (int c = 0; c < 3; ++c) vh[i][c] = zero;
    gemmV<2, 4>(W.a1_Wvh, 128, sv, vh);
    __syncthreads();
    #pragma unroll
    for (int i = 0; i < 2; ++i) {
      const int tile = wv + i * 8;
      for (int c = 0; c < 3; ++c) stCD(sv + c * PLANE, VSTR, tile, vh[i][c]);
      ffrag n;
      for (int r = 0; r < 4; ++r)
        n[r] = sqrtf(vh[i][0][r]*vh[i][0][r] + vh[i][1][r]*vh[i][1][r] + vh[i][2][r]*vh[i][2][r]);
      stCD(scat, SSTR, tile, n);
    }
    __syncthreads();

    // B: so = Ws @ scat[0:384]; ov[2] = Wvo(256) @ vh; raw_so -> souts
    ffrag so[1]; so[0] = zero;
    ffrag ov[2][3];
    #pragma unroll
    for (int i = 0; i < 2; ++i) for (int c = 0; c < 3; ++c) ov[i][c] = zero;
    gemmS<1, 12>(W.a1_Ws, 384, scat, SSTR, so);
    gemmV<2, 8>(W.a1_Wvo, 256, sv, ov);
    stCD(souts, OSTR, wv, so[0]);
    __syncthreads();

    // C: g[2] = Wg @ souts; gate both tiles; v_new -> sv[0:256]; act_s1 -> scat[128:256]
    ffrag g[2];
    #pragma unroll
    for (int i = 0; i < 2; ++i) g[i] = zero;
    gemmS<2, 4>(W.a1_Wg, 128, souts, OSTR, g);
    #pragma unroll
    for (int i = 0; i < 2; ++i) {
      const int tile = wv + i * 8;
      const float4 b = *(const float4*)(W.a1_bg + tile * 16 + q * 4);
      const float bb[4] = {b.x, b.y, b.z, b.w};
      for (int r = 0; r < 4; ++r) {
        float gg = sigm(g[i][r] + bb[r]);
        ov[i][0][r] *= gg; ov[i][1][r] *= gg; ov[i][2][r] *= gg;
      }
      for (int c = 0; c < 3; ++c) stCD(sv + c * PLANE, VSTR, tile, ov[i][c]);
    }
    {
      ffrag l;
      for (int r = 0; r < 4; ++r) { float x = so[0][r]; l[r] = x >= 0.f ? x : SLOPE_SCA * x; }
      stCD(scat + 128, SSTR, wv, l);
    }
    __syncthreads();

    // D: d[2] = Wd(256) @ v_new
    ffrag d[2][3];
    #pragma unroll
    for (int i = 0; i < 2; ++i) for (int c = 0; c < 3; ++c) d[i][c] = zero;
    gemmV<2, 8>(W.a1_Wd, 256, sv, d);
    __syncthreads();

    // E: vn_leaky per tile (x re-read), v1 -> sv[0:256]
    vnLeakyStore(sv, wv,     d[0][0], d[0][1], d[0][2]);
    vnLeakyStore(sv, wv + 8, d[1][0], d[1][1], d[1][2]);
    __syncthreads();
  }

  // ---- mid: inner[e][h] = <v1[128+h], relpos[e]> -> scat[256:384]
  //      (concurrent with a2's Wvh gemm: disjoint reads/writes) ----
  {
    const float r0 = srel[el * 3 + 0], r1 = srel[el * 3 + 1], r2 = srel[el * 3 + 2];
    for (int h = c5; h < 128; h += 32) {
      float x0 = (float)sv[0 * PLANE + el * VSTR + 128 + h];
      float x1 = (float)sv[1 * PLANE + el * VSTR + 128 + h];
      float x2 = (float)sv[2 * PLANE + el * VSTR + 128 + h];
      scat[el * SSTR + 256 + h] = (_Float16)(x0 * r0 + x1 * r1 + x2 * r2);
    }
  }

  // ================= a2: perceptron (v = v1[:,:128], s2 = [s1, inner]) =========
  {
    // A: vh = Wvh @ sv[0:128] (concurrent with mid above)
    ffrag vh[1][3];
    for (int c = 0; c < 3; ++c) vh[0][c] = zero;
    gemmV<1, 4>(W.a2_Wvh, 128, sv, vh);
    __syncthreads();                  // mid reads of sv[128:256] done
    // A-store: vh -> sv[128:256]; vnorm -> scat[0:128]
    for (int c = 0; c < 3; ++c) stCD(sv + c * PLANE + 128, VSTR, wv, vh[0][c]);
    {
      ffrag n;
      for (int r = 0; r < 4; ++r)
        n[r] = sqrtf(vh[0][0][r]*vh[0][0][r] + vh[0][1][r]*vh[0][1][r] + vh[0][2][r]*vh[0][2][r]);
      stCD(scat, SSTR, wv, n);
    }
    __syncthreads();

    // B: so = Ws @ scat[0:384]; ov = Wvo @ vh; raw_so -> souts
    ffrag so[1]; so[0] = zero;
    ffrag ov[1][3];
    for (int c = 0; c < 3; ++c) ov[0][c] = zero;
    gemmS<1, 12>(W.a2_Ws, 384, scat, SSTR, so);
    gemmV<1, 4>(W.a2_Wvo, 128, sv + 128, ov);
    stCD(souts, OSTR, wv, so[0]);
    __syncthreads();

    // C: g = Wg @ souts; gate; v_new -> sv[0:128]; act_s -> scat[128:256]
    ffrag g[1]; g[0] = zero;
    gemmS<1, 4>(W.a2_Wg, 128, souts, OSTR, g);
    {
      const float4 b = *(const float4*)(W.a2_bg + wv * 16 + q * 4);
      const float bb[4] = {b.x, b.y, b.z, b.w};
      for (int r = 0; r < 4; ++r) {
        float gg = sigm(g[0][r] + bb[r]);
        ov[0][0][r] *= gg; ov[0][1][r] *= gg; ov[0][2][r] *= gg;
      }
      for (int c = 0; c < 3; ++c) stCD(sv + c * PLANE, VSTR, wv, ov[0][c]);
      ffrag l;
      for (int r = 0; r < 4; ++r) { float x = so[0][r]; l[r] = x >= 0.f ? x : SLOPE_SCA * x; }
      stCD(scat + 128, SSTR, wv, l);
    }
    __syncthreads();

    // D: d = Wd @ v_new
    ffrag d[1][3];
    for (int c = 0; c < 3; ++c) d[0][c] = zero;
    gemmV<1, 4>(W.a2_Wd, 128, sv, d);
    __syncthreads();

    // E: vn_leaky, v_final -> sv[0:128]
    vnLeakyStore(sv, wv, d[0][0], d[0][1], d[0][2]);
    __syncthreads();
  }

  // ================= f: vnorm + final dot =================
  {
    ffrag vh[1][3];
    for (int c = 0; c < 3; ++c) vh[0][c] = zero;
    gemmV<1, 4>(W.f_Wvh, 128, sv, vh);
    {
      ffrag n;
      for (int r = 0; r < 4; ++r)
        n[r] = sqrtf(vh[0][0][r]*vh[0][0][r] + vh[0][1][r]*vh[0][1][r] + vh[0][2][r]*vh[0][2][r]);
      stCD(scat, SSTR, wv, n);
    }
    __syncthreads();

    float part = 0.f;
    for (int c = c5; c < 256; c += 32)
      part += (float)scat[el * SSTR + c] * W.f_Ws[c];
    part += __shfl_xor(part, 16, 32);
    part += __shfl_xor(part, 8, 32);
    part += __shfl_xor(part, 4, 32);
    part += __shfl_xor(part, 2, 32);
    part += __shfl_xor(part, 1, 32);
    if (c5 == 0 && eg < F) out[eg] = part;
  }
}

extern "C" void kernel_launch(void* const* d_in, const int* in_sizes, int n_in,
                              void* d_out, int out_size, void* d_ws, size_t ws_size,
                              hipStream_t stream) {
  const float* h_sca       = (const float*)d_in[0];
  const float* h_vec       = (const float*)d_in[1];
  const float* pos_compose = (const float*)d_in[2];
  const float* pos         = (const float*)d_in[3];
  const int* idx_focal     = (const int*)d_in[29];
  const int F = in_sizes[29];

  // weight conversion jobs: d_in index -> packed f16 in d_ws
  const int widx[20] = {4,5,6,7,9, 10,11,12,13, 15,16,17,18,20, 21,22,23,24,26, 27};
  CvtJobs J;
  _Float16* wsp = (_Float16*)d_ws;
  size_t off = 0;
  const _Float16* wptr[20];
  for (int j = 0; j < 20; ++j) {
    J.src[j] = (const float*)d_in[widx[j]];
    J.dst[j] = wsp + off;
    J.n[j]   = in_sizes[widx[j]];
    wptr[j]  = wsp + off;
    off += in_sizes[widx[j]];
  }
  cvt_kernel<<<dim3(32, 20), dim3(256), 0, stream>>>(J);

  WB W;
  W.g1_Wvh = wptr[0];  W.g1_Ws = wptr[1];  W.g1_Wvo = wptr[2];  W.g1_Wg = wptr[3];  W.g1_Wd = wptr[4];
  W.g2_Wvh = wptr[5];  W.g2_Ws = wptr[6];  W.g2_Wvo = wptr[7];  W.g2_Wg = wptr[8];
  W.a1_Wvh = wptr[9];  W.a1_Ws = wptr[10]; W.a1_Wvo = wptr[11]; W.a1_Wg = wptr[12]; W.a1_Wd = wptr[13];
  W.a2_Wvh = wptr[14]; W.a2_Ws = wptr[15]; W.a2_Wvo = wptr[16]; W.a2_Wg = wptr[17]; W.a2_Wd = wptr[18];
  W.f_Wvh  = wptr[19];
  W.g1_bg = (const float*)d_in[8];
  W.g2_bg = (const float*)d_in[14];
  W.a1_bg = (const float*)d_in[19];
  W.a2_bg = (const float*)d_in[25];
  W.f_Ws  = (const float*)d_in[28];

  const int blocks = (F + E - 1) / E;
  pe_kernel<<<dim3(blocks), dim3(TPB), 0, stream>>>(
      h_sca, h_vec, pos_compose, pos, W, idx_focal, (float*)d_out, F);
}

// Round 7
// 794.915 us; speedup vs baseline: 1.4367x; 1.4367x over previous
//
#include <hip/hip_runtime.h>
#include <math.h>

#define TPB 512        // 8 waves: wave w owns row-tile (w + t*8)
#define E 16           // elements per GROUP
#define G 2            // element-groups per block (E*G = 32 elements/block)
#define VSTR 264       // [e][k] stride for vector-activation LDS (f16)
#define PLANE (E * VSTR)     // one comp, one group
#define CPL (G * PLANE)      // comp stride
#define SSTR 392       // scat row stride
#define SLOPE_VN 0.2f
#define SLOPE_SCA 0.01f
#define EPS_VN 1e-6f

using hfrag = __attribute__((ext_vector_type(8))) _Float16;
using h4    = __attribute__((ext_vector_type(4))) _Float16;
using ffrag = __attribute__((ext_vector_type(4))) float;

__device__ __forceinline__ ffrag mfma(hfrag a, hfrag b, ffrag c) {
  return __builtin_amdgcn_mfma_f32_16x16x32_f16(a, b, c, 0, 0, 0);
}

// ---- f16 weight pointers (into d_ws) ----
struct WB {
  const _Float16 *g1_Wvh,*g1_Ws,*g1_Wvo,*g1_Wg,*g1_Wd;
  const _Float16 *g2_Wvh,*g2_Ws,*g2_Wvo,*g2_Wg;
  const _Float16 *a1_Wvh,*a1_Ws,*a1_Wvo,*a1_Wg,*a1_Wd;
  const _Float16 *a2_Wvh,*a2_Ws,*a2_Wvo,*a2_Wg,*a2_Wd;
  const _Float16 *f_Wvh;
  const float *g1_bg,*g2_bg,*a1_bg,*a2_bg,*f_Ws;
};

// ---- weight f32->f16 conversion pre-pass ----
struct CvtJobs { const float* src[20]; _Float16* dst[20]; int n[20]; };

__global__ void cvt_kernel(CvtJobs J) {
  const int j = blockIdx.y;
  const float* __restrict__ s = J.src[j];
  _Float16* __restrict__ d = J.dst[j];
  const int n = J.n[j];
  for (int i = blockIdx.x * blockDim.x + threadIdx.x; i < n;
       i += gridDim.x * blockDim.x)
    d[i] = (_Float16)s[i];
}

// ---- GEMM helpers: one A-fragment feeds BOTH element-groups ----
// Vector GEMM: acc[g][t][c] += W[O][C] * v_c(group g), tiles = wave + 8*t.
template<int TT, int KS>
__device__ __forceinline__ void gemmV2(const _Float16* __restrict__ W, int C,
                                       const _Float16* vb, ffrag acc[G][TT][3]) {
  const int m = threadIdx.x & 15;
  const int q = (threadIdx.x >> 4) & 3;
  const int w = threadIdx.x >> 6;
  #pragma unroll
  for (int ks = 0; ks < KS; ++ks) {
    const int k = ks * 32 + q * 8;
    hfrag a[TT];
    #pragma unroll
    for (int t = 0; t < TT; ++t)
      a[t] = *(const hfrag*)(W + (size_t)((w + t * 8) * 16 + m) * C + k);
    #pragma unroll
    for (int g = 0; g < G; ++g) {
      hfrag b0 = *(const hfrag*)(vb + 0 * CPL + g * PLANE + m * VSTR + k);
      hfrag b1 = *(const hfrag*)(vb + 1 * CPL + g * PLANE + m * VSTR + k);
      hfrag b2 = *(const hfrag*)(vb + 2 * CPL + g * PLANE + m * VSTR + k);
      #pragma unroll
      for (int t = 0; t < TT; ++t) {
        acc[g][t][0] = mfma(a[t], b0, acc[g][t][0]);
        acc[g][t][1] = mfma(a[t], b1, acc[g][t][1]);
        acc[g][t][2] = mfma(a[t], b2, acc[g][t][2]);
      }
    }
  }
}

// Scalar GEMM: acc[g][t] += W[O][C] * s(group g)
template<int TT, int KS>
__device__ __forceinline__ void gemmS2(const _Float16* __restrict__ W, int C,
                                       const _Float16* sb, ffrag acc[G][TT]) {
  const int m = threadIdx.x & 15;
  const int q = (threadIdx.x >> 4) & 3;
  const int w = threadIdx.x >> 6;
  #pragma unroll
  for (int ks = 0; ks < KS; ++ks) {
    const int k = ks * 32 + q * 8;
    hfrag a[TT];
    #pragma unroll
    for (int t = 0; t < TT; ++t)
      a[t] = *(const hfrag*)(W + (size_t)((w + t * 8) * 16 + m) * C + k);
    #pragma unroll
    for (int g = 0; g < G; ++g) {
      hfrag b = *(const hfrag*)(sb + g * E * SSTR + m * SSTR + k);
      #pragma unroll
      for (int t = 0; t < TT; ++t)
        acc[g][t] = mfma(a[t], b, acc[g][t]);
    }
  }
}

// Store a C/D fragment into an [e][k] LDS buffer (4 consecutive k = rows).
__device__ __forceinline__ void stCD(_Float16* buf, int stride, int tile, ffrag v) {
  const int e = threadIdx.x & 15;
  const int q = (threadIdx.x >> 4) & 3;
  h4 p;
  p[0] = (_Float16)v[0]; p[1] = (_Float16)v[1];
  p[2] = (_Float16)v[2]; p[3] = (_Float16)v[3];
  *(h4*)(buf + e * stride + tile * 16 + q * 4) = p;
}

// Re-load a C/D fragment (this wave's own tile) from LDS.
__device__ __forceinline__ ffrag ldCD(const _Float16* buf, int stride, int tile) {
  const int e = threadIdx.x & 15;
  const int q = (threadIdx.x >> 4) & 3;
  h4 p = *(const h4*)(buf + e * stride + tile * 16 + q * 4);
  ffrag v;
  v[0] = (float)p[0]; v[1] = (float)p[1]; v[2] = (float)p[2]; v[3] = (float)p[3];
  return v;
}

__device__ __forceinline__ float sigm(float x) { return 1.f / (1.f + expf(-x)); }

// vn_leaky on re-read x (f16, self-consistent with Wd input) + d, store result.
// svg = sv + g*PLANE; comp stride CPL.
__device__ __forceinline__ void vnLeakyStoreG(_Float16* svg, int tile,
                                              ffrag d0, ffrag d1, ffrag d2) {
  ffrag x0 = ldCD(svg + 0 * CPL, VSTR, tile);
  ffrag x1 = ldCD(svg + 1 * CPL, VSTR, tile);
  ffrag x2 = ldCD(svg + 2 * CPL, VSTR, tile);
  #pragma unroll
  for (int r = 0; r < 4; ++r) {
    float dot = x0[r]*d0[r] + x1[r]*d1[r] + x2[r]*d2[r];
    float kk = dot / (d0[r]*d0[r] + d1[r]*d1[r] + d2[r]*d2[r] + EPS_VN);
    if (dot < 0.f) {
      x0[r] = SLOPE_VN*x0[r] + (1.f-SLOPE_VN)*(x0[r] - kk*d0[r]);
      x1[r] = SLOPE_VN*x1[r] + (1.f-SLOPE_VN)*(x1[r] - kk*d1[r]);
      x2[r] = SLOPE_VN*x2[r] + (1.f-SLOPE_VN)*(x2[r] - kk*d2[r]);
    }
  }
  stCD(svg + 0 * CPL, VSTR, tile, x0);
  stCD(svg + 1 * CPL, VSTR, tile, x1);
  stCD(svg + 2 * CPL, VSTR, tile, x2);
}

__global__ __launch_bounds__(TPB, 4) void pe_kernel(
    const float* __restrict__ h_sca, const float* __restrict__ h_vec,
    const float* __restrict__ pos_compose, const float* __restrict__ pos,
    WB W, const int* __restrict__ idx_focal, float* __restrict__ out, int F) {
  // sv: [comp][group][e][k<264]. scat: [group][e][k<392]:
  //   vnorm[0:128(/256 a1)] | s/act_s[128:256] | raw_so / g2_raw / inner [256:384]
  __shared__ _Float16 sv [3 * CPL];
  __shared__ _Float16 scat[G * E * SSTR];
  __shared__ float srel[G * E * 3];

  const int t = threadIdx.x;
  const int wv = t >> 6;          // 0..7
  const int q = (t >> 4) & 3;
  const int el = t >> 4;          // gather/mid/out: element (0..31), 16 thr each
  const int c4 = t & 15;
  const int eg = blockIdx.x * (E * G) + el;

  // ======== gather (f32 -> f16 LDS, float4 loads, h4 stores) ========
  {
    const int idx = (eg < F) ? idx_focal[eg] : 0;
    // h_vec row = 64 cols x 3 comps; thread c4 handles cols 4c4..4c4+3
    const float4* __restrict__ vsrc = (const float4*)(h_vec + (size_t)idx * 192);
    const float4 va = vsrc[3 * c4 + 0];
    const float4 vb = vsrc[3 * c4 + 1];
    const float4 vc = vsrc[3 * c4 + 2];
    const float f[12] = {va.x, va.y, va.z, va.w, vb.x, vb.y, vb.z, vb.w,
                         vc.x, vc.y, vc.z, vc.w};
    #pragma unroll
    for (int comp = 0; comp < 3; ++comp) {
      h4 p;
      p[0] = (_Float16)f[0 + comp]; p[1] = (_Float16)f[3 + comp];
      p[2] = (_Float16)f[6 + comp]; p[3] = (_Float16)f[9 + comp];
      *(h4*)(sv + comp * CPL + el * VSTR + 4 * c4) = p;
    }
    // h_sca row = 256 floats; thread c4 handles cols 16c4..16c4+15
    const float4* __restrict__ ssrc = (const float4*)(h_sca + (size_t)idx * 256);
    #pragma unroll
    for (int i2 = 0; i2 < 4; ++i2) {
      const float4 vv = ssrc[4 * c4 + i2];
      h4 p;
      p[0] = (_Float16)vv.x; p[1] = (_Float16)vv.y;
      p[2] = (_Float16)vv.z; p[3] = (_Float16)vv.w;
      *(h4*)(scat + el * SSTR + 128 + 16 * c4 + 4 * i2) = p;
    }
    if (c4 < 3 && eg < F)
      srel[el * 3 + c4] = pos[(size_t)eg * 3 + c4] - pos_compose[(size_t)idx * 3 + c4];
  }
  __syncthreads();

  ffrag zero = {0.f, 0.f, 0.f, 0.f};

  // ================= g1: perceptron (C=64 -> H=128 -> O=128) =================
  {
    // A: vh = Wvh @ v_in[0:64]; vh -> sv[64:192]; vnorm -> scat[0:128]
    ffrag vh[G][1][3];
    #pragma unroll
    for (int g = 0; g < G; ++g) for (int c = 0; c < 3; ++c) vh[g][0][c] = zero;
    gemmV2<1, 2>(W.g1_Wvh, 64, sv, vh);
    #pragma unroll
    for (int g = 0; g < G; ++g) {
      for (int c = 0; c < 3; ++c)
        stCD(sv + c * CPL + g * PLANE + 64, VSTR, wv, vh[g][0][c]);
      ffrag n;
      #pragma unroll
      for (int r = 0; r < 4; ++r)
        n[r] = sqrtf(vh[g][0][0][r]*vh[g][0][0][r] + vh[g][0][1][r]*vh[g][0][1][r] + vh[g][0][2][r]*vh[g][0][2][r]);
      stCD(scat + g * E * SSTR, SSTR, wv, n);
    }
    __syncthreads();

    // B: so = Ws @ scat[0:384]; ov = Wvo @ vh
    ffrag so[G][1]; ffrag ov[G][1][3];
    #pragma unroll
    for (int g = 0; g < G; ++g) { so[g][0] = zero; for (int c = 0; c < 3; ++c) ov[g][0][c] = zero; }
    gemmS2<1, 12>(W.g1_Ws, 384, scat, so);
    gemmV2<1, 4>(W.g1_Wvo, 128, sv + 64, ov);
    __syncthreads();

    // C1: raw_so -> scat[256:384] (s_in tail dead)
    #pragma unroll
    for (int g = 0; g < G; ++g) stCD(scat + g * E * SSTR + 256, SSTR, wv, so[g][0]);
    __syncthreads();

    // C2: gate = Wg @ raw; v_new -> sv[0:128]; act_s -> scat[128:256]
    ffrag gg[G][1];
    #pragma unroll
    for (int g = 0; g < G; ++g) gg[g][0] = zero;
    gemmS2<1, 4>(W.g1_Wg, 128, scat + 256, gg);
    {
      const float4 b = *(const float4*)(W.g1_bg + wv * 16 + q * 4);
      const float bb[4] = {b.x, b.y, b.z, b.w};
      #pragma unroll
      for (int g = 0; g < G; ++g) {
        #pragma unroll
        for (int r = 0; r < 4; ++r) {
          float s2 = sigm(gg[g][0][r] + bb[r]);
          ov[g][0][0][r] *= s2; ov[g][0][1][r] *= s2; ov[g][0][2][r] *= s2;
        }
        for (int c = 0; c < 3; ++c) stCD(sv + c * CPL + g * PLANE, VSTR, wv, ov[g][0][c]);
        ffrag l;
        for (int r = 0; r < 4; ++r) { float x = so[g][0][r]; l[r] = x >= 0.f ? x : SLOPE_SCA * x; }
        stCD(scat + g * E * SSTR + 128, SSTR, wv, l);
      }
    }
    __syncthreads();

    // D: d = Wd @ v_new
    ffrag d[G][1][3];
    #pragma unroll
    for (int g = 0; g < G; ++g) for (int c = 0; c < 3; ++c) d[g][0][c] = zero;
    gemmV2<1, 4>(W.g1_Wd, 128, sv, d);
    __syncthreads();

    // E: vn_leaky
    #pragma unroll
    for (int g = 0; g < G; ++g)
      vnLeakyStoreG(sv + g * PLANE, wv, d[g][0][0], d[g][0][1], d[g][0][2]);
    __syncthreads();
  }

  // ================= g2: linear (128 -> 128) =================
  {
    ffrag vh[G][1][3];
    #pragma unroll
    for (int g = 0; g < G; ++g) for (int c = 0; c < 3; ++c) vh[g][0][c] = zero;
    gemmV2<1, 4>(W.g2_Wvh, 128, sv, vh);
    #pragma unroll
    for (int g = 0; g < G; ++g) {
      for (int c = 0; c < 3; ++c)
        stCD(sv + c * CPL + g * PLANE + 128, VSTR, wv, vh[g][0][c]);
      ffrag n;
      for (int r = 0; r < 4; ++r)
        n[r] = sqrtf(vh[g][0][0][r]*vh[g][0][0][r] + vh[g][0][1][r]*vh[g][0][1][r] + vh[g][0][2][r]*vh[g][0][2][r]);
      stCD(scat + g * E * SSTR, SSTR, wv, n);
    }
    __syncthreads();

    // B: Ws reads scat[0:256] only -> raw_so can go to [256:384] pre-barrier
    ffrag so[G][1]; ffrag ov[G][1][3];
    #pragma unroll
    for (int g = 0; g < G; ++g) { so[g][0] = zero; for (int c = 0; c < 3; ++c) ov[g][0][c] = zero; }
    gemmS2<1, 8>(W.g2_Ws, 256, scat, so);
    gemmV2<1, 4>(W.g2_Wvo, 128, sv + 128, ov);
    #pragma unroll
    for (int g = 0; g < G; ++g) stCD(scat + g * E * SSTR + 256, SSTR, wv, so[g][0]);
    __syncthreads();

    // C: gate; v_final -> sv[0:128]. raw stays at [256:384] = a1's s input.
    ffrag gg[G][1];
    #pragma unroll
    for (int g = 0; g < G; ++g) gg[g][0] = zero;
    gemmS2<1, 4>(W.g2_Wg, 128, scat + 256, gg);
    {
      const float4 b = *(const float4*)(W.g2_bg + wv * 16 + q * 4);
      const float bb[4] = {b.x, b.y, b.z, b.w};
      #pragma unroll
      for (int g = 0; g < G; ++g) {
        for (int r = 0; r < 4; ++r) {
          float s2 = sigm(gg[g][0][r] + bb[r]);
          ov[g][0][0][r] *= s2; ov[g][0][1][r] *= s2; ov[g][0][2][r] *= s2;
        }
        for (int c = 0; c < 3; ++c) stCD(sv + c * CPL + g * PLANE, VSTR, wv, ov[g][0][c]);
      }
    }
    __syncthreads();
  }

  // ================= a1: perceptron (128 -> H=256 -> O=256) =================
  {
    // A1: vh[2 tiles] = Wvh @ v_in[0:128]
    ffrag vh[G][2][3];
    #pragma unroll
    for (int g = 0; g < G; ++g) for (int i = 0; i < 2; ++i)
      for (int c = 0; c < 3; ++c) vh[g][i][c] = zero;
    gemmV2<2, 4>(W.a1_Wvh, 128, sv, vh);
    __syncthreads();
    // A2: vh -> sv[0:256]; vnorm -> scat[0:256]
    #pragma unroll
    for (int g = 0; g < G; ++g)
      #pragma unroll
      for (int i = 0; i < 2; ++i) {
        const int tile = wv + i * 8;
        for (int c = 0; c < 3; ++c)
          stCD(sv + c * CPL + g * PLANE, VSTR, tile, vh[g][i][c]);
        ffrag n;
        for (int r = 0; r < 4; ++r)
          n[r] = sqrtf(vh[g][i][0][r]*vh[g][i][0][r] + vh[g][i][1][r]*vh[g][i][1][r] + vh[g][i][2][r]*vh[g][i][2][r]);
        stCD(scat + g * E * SSTR, SSTR, tile, n);
      }
    __syncthreads();

    // B: so = Ws @ scat[0:384]; ov[2] = Wvo(256) @ vh
    ffrag so[G][1]; ffrag ov[G][2][3];
    #pragma unroll
    for (int g = 0; g < G; ++g) {
      so[g][0] = zero;
      for (int i = 0; i < 2; ++i) for (int c = 0; c < 3; ++c) ov[g][i][c] = zero;
    }
    gemmS2<1, 12>(W.a1_Ws, 384, scat, so);
    gemmV2<2, 8>(W.a1_Wvo, 256, sv, ov);
    __syncthreads();

    // C1: raw_so -> scat[256:384] (g2 raw dead)
    #pragma unroll
    for (int g = 0; g < G; ++g) stCD(scat + g * E * SSTR + 256, SSTR, wv, so[g][0]);
    __syncthreads();

    // C2: g[2] = Wg @ raw; gate both tiles; v_new -> sv[0:256]; act_s1 -> scat[128:256]
    ffrag gg[G][2];
    #pragma unroll
    for (int g = 0; g < G; ++g) for (int i = 0; i < 2; ++i) gg[g][i] = zero;
    gemmS2<2, 4>(W.a1_Wg, 128, scat + 256, gg);
    #pragma unroll
    for (int g = 0; g < G; ++g) {
      #pragma unroll
      for (int i = 0; i < 2; ++i) {
        const int tile = wv + i * 8;
        const float4 b = *(const float4*)(W.a1_bg + tile * 16 + q * 4);
        const float bb[4] = {b.x, b.y, b.z, b.w};
        for (int r = 0; r < 4; ++r) {
          float s2 = sigm(gg[g][i][r] + bb[r]);
          ov[g][i][0][r] *= s2; ov[g][i][1][r] *= s2; ov[g][i][2][r] *= s2;
        }
        for (int c = 0; c < 3; ++c)
          stCD(sv + c * CPL + g * PLANE, VSTR, tile, ov[g][i][c]);
      }
      ffrag l;
      for (int r = 0; r < 4; ++r) { float x = so[g][0][r]; l[r] = x >= 0.f ? x : SLOPE_SCA * x; }
      stCD(scat + g * E * SSTR + 128, SSTR, wv, l);
    }
    __syncthreads();

    // D: d[2] = Wd(256) @ v_new
    ffrag d[G][2][3];
    #pragma unroll
    for (int g = 0; g < G; ++g) for (int i = 0; i < 2; ++i)
      for (int c = 0; c < 3; ++c) d[g][i][c] = zero;
    gemmV2<2, 8>(W.a1_Wd, 256, sv, d);
    __syncthreads();

    // E: vn_leaky per tile per group -> v1 in sv[0:256]
    #pragma unroll
    for (int g = 0; g < G; ++g) {
      vnLeakyStoreG(sv + g * PLANE, wv,     d[g][0][0], d[g][0][1], d[g][0][2]);
      vnLeakyStoreG(sv + g * PLANE, wv + 8, d[g][1][0], d[g][1][1], d[g][1][2]);
    }
    __syncthreads();
  }

  // ---- mid: inner[e][h] = <v1[128+h], relpos[e]> -> scat[256:384]
  //      (concurrent with a2's Wvh gemm: disjoint reads/writes) ----
  {
    const float r0 = srel[el * 3 + 0], r1 = srel[el * 3 + 1], r2 = srel[el * 3 + 2];
    for (int h = c4; h < 128; h += 16) {
      float x0 = (float)sv[0 * CPL + el * VSTR + 128 + h];
      float x1 = (float)sv[1 * CPL + el * VSTR + 128 + h];
      float x2 = (float)sv[2 * CPL + el * VSTR + 128 + h];
      scat[el * SSTR + 256 + h] = (_Float16)(x0 * r0 + x1 * r1 + x2 * r2);
    }
  }

  // ================= a2: perceptron (v = v1[:,:128], s2 = [s1, inner]) =========
  {
    // A1: vh = Wvh @ sv[0:128] (concurrent with mid)
    ffrag vh[G][1][3];
    #pragma unroll
    for (int g = 0; g < G; ++g) for (int c = 0; c < 3; ++c) vh[g][0][c] = zero;
    gemmV2<1, 4>(W.a2_Wvh, 128, sv, vh);
    __syncthreads();                  // mid writes + mid's sv reads done
    // A2: vh -> sv[128:256]; vnorm -> scat[0:128]
    #pragma unroll
    for (int g = 0; g < G; ++g) {
      for (int c = 0; c < 3; ++c)
        stCD(sv + c * CPL + g * PLANE + 128, VSTR, wv, vh[g][0][c]);
      ffrag n;
      for (int r = 0; r < 4; ++r)
        n[r] = sqrtf(vh[g][0][0][r]*vh[g][0][0][r] + vh[g][0][1][r]*vh[g][0][1][r] + vh[g][0][2][r]*vh[g][0][2][r]);
      stCD(scat + g * E * SSTR, SSTR, wv, n);
    }
    __syncthreads();

    // B: so = Ws @ scat[0:384] (vnorm|s1|inner); ov = Wvo @ vh
    ffrag so[G][1]; ffrag ov[G][1][3];
    #pragma unroll
    for (int g = 0; g < G; ++g) { so[g][0] = zero; for (int c = 0; c < 3; ++c) ov[g][0][c] = zero; }
    gemmS2<1, 12>(W.a2_Ws, 384, scat, so);
    gemmV2<1, 4>(W.a2_Wvo, 128, sv + 128, ov);
    __syncthreads();

    // C1: raw_so -> scat[256:384] (inner dead)
    #pragma unroll
    for (int g = 0; g < G; ++g) stCD(scat + g * E * SSTR + 256, SSTR, wv, so[g][0]);
    __syncthreads();

    // C2: gate; v_new -> sv[0:128]; act_s -> scat[128:256]
    ffrag gg[G][1];
    #pragma unroll
    for (int g = 0; g < G; ++g) gg[g][0] = zero;
    gemmS2<1, 4>(W.a2_Wg, 128, scat + 256, gg);
    {
      const float4 b = *(const float4*)(W.a2_bg + wv * 16 + q * 4);
      const float bb[4] = {b.x, b.y, b.z, b.w};
      #pragma unroll
      for (int g = 0; g < G; ++g) {
        for (int r = 0; r < 4; ++r) {
          float s2 = sigm(gg[g][0][r] + bb[r]);
          ov[g][0][0][r] *= s2; ov[g][0][1][r] *= s2; ov[g][0][2][r] *= s2;
        }
        for (int c = 0; c < 3; ++c) stCD(sv + c * CPL + g * PLANE, VSTR, wv, ov[g][0][c]);
        ffrag l;
        for (int r = 0; r < 4; ++r) { float x = so[g][0][r]; l[r] = x >= 0.f ? x : SLOPE_SCA * x; }
        stCD(scat + g * E * SSTR + 128, SSTR, wv, l);
      }
    }
    __syncthreads();

    // D: d = Wd @ v_new
    ffrag d[G][1][3];
    #pragma unroll
    for (int g = 0; g < G; ++g) for (int c = 0; c < 3; ++c) d[g][0][c] = zero;
    gemmV2<1, 4>(W.a2_Wd, 128, sv, d);
    __syncthreads();

    // E: vn_leaky
    #pragma unroll
    for (int g = 0; g < G; ++g)
      vnLeakyStoreG(sv + g * PLANE, wv, d[g][0][0], d[g][0][1], d[g][0][2]);
    __syncthreads();
  }

  // ================= f: vnorm + final dot =================
  {
    ffrag vh[G][1][3];
    #pragma unroll
    for (int g = 0; g < G; ++g) for (int c = 0; c < 3; ++c) vh[g][0][c] = zero;
    gemmV2<1, 4>(W.f_Wvh, 128, sv, vh);
    #pragma unroll
    for (int g = 0; g < G; ++g) {
      ffrag n;
      for (int r = 0; r < 4; ++r)
        n[r] = sqrtf(vh[g][0][0][r]*vh[g][0][0][r] + vh[g][0][1][r]*vh[g][0][1][r] + vh[g][0][2][r]*vh[g][0][2][r]);
      stCD(scat + g * E * SSTR, SSTR, wv, n);
    }
    __syncthreads();

    float part = 0.f;
    for (int c = c4; c < 256; c += 16)
      part += (float)scat[el * SSTR + c] * W.f_Ws[c];
    part += __shfl_xor(part, 8, 16);
    part += __shfl_xor(part, 4, 16);
    part += __shfl_xor(part, 2, 16);
    part += __shfl_xor(part, 1, 16);
    if (c4 == 0 && eg < F) out[eg] = part;
  }
}

extern "C" void kernel_launch(void* const* d_in, const int* in_sizes, int n_in,
                              void* d_out, int out_size, void* d_ws, size_t ws_size,
                              hipStream_t stream) {
  const float* h_sca       = (const float*)d_in[0];
  const float* h_vec       = (const float*)d_in[1];
  const float* pos_compose = (const float*)d_in[2];
  const float* pos         = (const float*)d_in[3];
  const int* idx_focal     = (const int*)d_in[29];
  const int F = in_sizes[29];

  // weight conversion jobs: d_in index -> packed f16 in d_ws
  const int widx[20] = {4,5,6,7,9, 10,11,12,13, 15,16,17,18,20, 21,22,23,24,26, 27};
  CvtJobs J;
  _Float16* wsp = (_Float16*)d_ws;
  size_t off = 0;
  const _Float16* wptr[20];
  for (int j = 0; j < 20; ++j) {
    J.src[j] = (const float*)d_in[widx[j]];
    J.dst[j] = wsp + off;
    J.n[j]   = in_sizes[widx[j]];
    wptr[j]  = wsp + off;
    off += in_sizes[widx[j]];
  }
  cvt_kernel<<<dim3(32, 20), dim3(256), 0, stream>>>(J);

  WB W;
  W.g1_Wvh = wptr[0];  W.g1_Ws = wptr[1];  W.g1_Wvo = wptr[2];  W.g1_Wg = wptr[3];  W.g1_Wd = wptr[4];
  W.g2_Wvh = wptr[5];  W.g2_Ws = wptr[6];  W.g2_Wvo = wptr[7];  W.g2_Wg = wptr[8];
  W.a1_Wvh = wptr[9];  W.a1_Ws = wptr[10]; W.a1_Wvo = wptr[11]; W.a1_Wg = wptr[12]; W.a1_Wd = wptr[13];
  W.a2_Wvh = wptr[14]; W.a2_Ws = wptr[15]; W.a2_Wvo = wptr[16]; W.a2_Wg = wptr[17]; W.a2_Wd = wptr[18];
  W.f_Wvh  = wptr[19];
  W.g1_bg = (const float*)d_in[8];
  W.g2_bg = (const float*)d_in[14];
  W.a1_bg = (const float*)d_in[19];
  W.a2_bg = (const float*)d_in[25];
  W.f_Ws  = (const float*)d_in[28];

  const int blocks = (F + E * G - 1) / (E * G);
  pe_kernel<<<dim3(blocks), dim3(TPB), 0, stream>>>(
      h_sca, h_vec, pos_compose, pos, W, idx_focal, (float*)d_out, F);
}